// Round 19
// baseline (194.038 us; speedup 1.0000x reference)
//
#include <hip/hip_runtime.h>

#define DF 128
#define SCHUNK 2048

typedef __attribute__((ext_vector_type(8))) short short8;
typedef __attribute__((ext_vector_type(4))) float f32x4;

__device__ __forceinline__ ushort f2bf(float f) {
    unsigned u = __float_as_uint(f);
    return (ushort)((u + 0x7fffu + ((u >> 16) & 1u)) >> 16);   // RNE
}
__device__ __forceinline__ float bf2f(ushort h) {
    return __uint_as_float(((unsigned)h) << 16);
}
__device__ __forceinline__ short8 ld_a_f32(const float* p) {
    const float4 u = ((const float4*)p)[0];
    const float4 v = ((const float4*)p)[1];
    short8 r;
    r[0] = (short)f2bf(u.x); r[1] = (short)f2bf(u.y);
    r[2] = (short)f2bf(u.z); r[3] = (short)f2bf(u.w);
    r[4] = (short)f2bf(v.x); r[5] = (short)f2bf(v.y);
    r[6] = (short)f2bf(v.z); r[7] = (short)f2bf(v.w);
    return r;
}

// ---------------- prep_all: weight fragments + zero bhist/g ----------------
__global__ __launch_bounds__(256) void prep_all(const float* __restrict__ Wpool0,
                                                const float* __restrict__ Wpool1,
                                                const float* __restrict__ Wself0,
                                                const float* __restrict__ Wneigh0,
                                                const float* __restrict__ Wself1,
                                                const float* __restrict__ Wneigh1,
                                                ushort* __restrict__ wfp0,
                                                ushort* __restrict__ wfp1,
                                                ushort* __restrict__ wfc0,
                                                ushort* __restrict__ wfc1,
                                                int* __restrict__ bhist,
                                                unsigned* __restrict__ g)
{
    const int tid = threadIdx.x;
    if (blockIdx.x == 48) {
        bhist[tid] = 0;
        if (tid < DF) g[tid] = 0;
        return;
    }
    const int e = blockIdx.x * 256 + tid;
    const float *Wa, *Wb; ushort* out; int le;
    if (e < 2048)      { Wa = Wpool0; Wb = Wpool0;  out = wfp0; le = e; }
    else if (e < 4096) { Wa = Wpool1; Wb = Wpool1;  out = wfp1; le = e - 2048; }
    else if (e < 8192) { Wa = Wself0; Wb = Wneigh0; out = wfc0; le = e - 4096; }
    else               { Wa = Wself1; Wb = Wneigh1; out = wfc1; le = e - 8192; }
    const int kstep = le >> 9;
    const int cb = (le >> 6) & 7;
    const int lane = le & 63;
    const int c = cb * 16 + (lane & 15);
    const int k0 = kstep * 32 + ((lane >> 4) << 3);
    ushort r[8];
    #pragma unroll
    for (int i = 0; i < 8; ++i) {
        const int k = k0 + i;
        const float v = (k < DF) ? Wa[k * DF + c] : Wb[(k - DF) * DF + c];
        r[i] = f2bf(v);
    }
    uint4 o;
    o.x = r[0] | ((unsigned)r[1] << 16);
    o.y = r[2] | ((unsigned)r[3] << 16);
    o.z = r[4] | ((unsigned)r[5] << 16);
    o.w = r[6] | ((unsigned)r[7] << 16);
    ((uint4*)out)[le] = o;
}

// ---------------- MFMA pool GEMM: out = relu(x @ Wpool + b), 128 rows/block ----------------
// B fragments read DIRECTLY from global (L2-resident, 1KB coalesced per wave-fragment).
// LDS used only for output staging (32KB).
template<int AF32>
__global__ __launch_bounds__(256) void gemm_pool(const ushort* __restrict__ xb,
                                                 const float* __restrict__ xf,
                                                 const ushort* __restrict__ wf,
                                                 const float* __restrict__ bias,
                                                 ushort* __restrict__ out, int nrows)
{
    __shared__ ushort ol[16384];
    __shared__ float bs[DF];
    const int tid = threadIdx.x;
    if (tid < DF) bs[tid] = bias[tid];
    __syncthreads();

    const int lane = tid & 63;
    const int w = tid >> 6;
    const int rb = blockIdx.x * 128 + w * 32;
    const int ar0 = min(rb + (lane & 15), nrows - 1);
    const int ar1 = min(rb + 16 + (lane & 15), nrows - 1);
    const int ko = (lane >> 4) << 3;
    const short8* wfv = (const short8*)wf;

    f32x4 acc[2][8];
    #pragma unroll
    for (int tt = 0; tt < 2; ++tt)
        #pragma unroll
        for (int cb = 0; cb < 8; ++cb) acc[tt][cb] = (f32x4){0.f, 0.f, 0.f, 0.f};

    #pragma unroll
    for (int ks = 0; ks < 4; ++ks) {
        short8 a0, a1;
        if (AF32) {
            a0 = ld_a_f32(xf + (size_t)ar0 * DF + ko + ks * 32);
            a1 = ld_a_f32(xf + (size_t)ar1 * DF + ko + ks * 32);
        } else {
            a0 = *(const short8*)(xb + (size_t)ar0 * DF + ko + ks * 32);
            a1 = *(const short8*)(xb + (size_t)ar1 * DF + ko + ks * 32);
        }
        #pragma unroll
        for (int cb = 0; cb < 8; ++cb) {
            const short8 b = wfv[(ks * 8 + cb) * 64 + lane];
            acc[0][cb] = __builtin_amdgcn_mfma_f32_16x16x32_bf16(a0, b, acc[0][cb], 0, 0, 0);
            acc[1][cb] = __builtin_amdgcn_mfma_f32_16x16x32_bf16(a1, b, acc[1][cb], 0, 0, 0);
        }
    }

    #pragma unroll
    for (int tt = 0; tt < 2; ++tt)
        #pragma unroll
        for (int cb = 0; cb < 8; ++cb) {
            const int c = (lane & 15) + (cb << 4);
            const float bv = bs[c];
            #pragma unroll
            for (int reg = 0; reg < 4; ++reg) {
                const int m = ((lane >> 4) << 2) + reg;
                ol[(w * 32 + tt * 16 + m) * DF + c] = f2bf(fmaxf(acc[tt][cb][reg] + bv, 0.f));
            }
        }
    __syncthreads();

    const int rowbase = blockIdx.x * 128;
    uint4* og = (uint4*)(out + (size_t)rowbase * DF);
    const uint4* olv = (const uint4*)ol;
    #pragma unroll
    for (int i = 0; i < 8; ++i) {
        const int j = tid + 256 * i;
        if (rowbase + (j >> 4) < nrows) og[j] = olv[j];
    }
}

// ---------------- MFMA fused GEMM+LN, 128 rows/block, direct-global B ----------------
// COLMAX=0: write out rows. COLMAX=1: skip global write, column-max -> atomicMax(g).
template<int AF32, int COLMAX>
__global__ __launch_bounds__(256) void gemm_fused_ln(const ushort* __restrict__ xb,
                                                     const float* __restrict__ xf,
                                                     const ushort* __restrict__ nbuf,
                                                     const ushort* __restrict__ wf,
                                                     const float* __restrict__ bias,
                                                     const float* __restrict__ gamma,
                                                     const float* __restrict__ beta,
                                                     ushort* __restrict__ out,
                                                     unsigned* __restrict__ g, int nrows)
{
    __shared__ ushort ol[16384];
    __shared__ float bs[DF], gs[DF], bt[DF];
    __shared__ unsigned cm[DF];
    const int tid = threadIdx.x;
    if (tid < DF) { bs[tid] = bias[tid]; gs[tid] = gamma[tid]; bt[tid] = beta[tid]; }
    if (COLMAX && tid < DF) cm[tid] = 0;
    __syncthreads();

    const int lane = tid & 63;
    const int w = tid >> 6;
    const int rb = blockIdx.x * 128 + w * 32;
    const int ar0 = min(rb + (lane & 15), nrows - 1);
    const int ar1 = min(rb + 16 + (lane & 15), nrows - 1);
    const int ko = (lane >> 4) << 3;
    const ushort* apn0 = nbuf + (size_t)ar0 * DF + ko;
    const ushort* apn1 = nbuf + (size_t)ar1 * DF + ko;
    const short8* wfv = (const short8*)wf;

    f32x4 acc[2][8];
    #pragma unroll
    for (int tt = 0; tt < 2; ++tt)
        #pragma unroll
        for (int cb = 0; cb < 8; ++cb) acc[tt][cb] = (f32x4){0.f, 0.f, 0.f, 0.f};

    #pragma unroll
    for (int ks = 0; ks < 8; ++ks) {
        short8 a0, a1;
        if (ks < 4) {
            if (AF32) {
                a0 = ld_a_f32(xf + (size_t)ar0 * DF + ko + ks * 32);
                a1 = ld_a_f32(xf + (size_t)ar1 * DF + ko + ks * 32);
            } else {
                a0 = *(const short8*)(xb + (size_t)ar0 * DF + ko + ks * 32);
                a1 = *(const short8*)(xb + (size_t)ar1 * DF + ko + ks * 32);
            }
        } else {
            a0 = *(const short8*)(apn0 + (ks - 4) * 32);
            a1 = *(const short8*)(apn1 + (ks - 4) * 32);
        }
        #pragma unroll
        for (int cb = 0; cb < 8; ++cb) {
            const short8 b = wfv[(ks * 8 + cb) * 64 + lane];
            acc[0][cb] = __builtin_amdgcn_mfma_f32_16x16x32_bf16(a0, b, acc[0][cb], 0, 0, 0);
            acc[1][cb] = __builtin_amdgcn_mfma_f32_16x16x32_bf16(a1, b, acc[1][cb], 0, 0, 0);
        }
    }

    float mu[2][4], inv[2][4];
    #pragma unroll
    for (int tt = 0; tt < 2; ++tt) {
        #pragma unroll
        for (int cb = 0; cb < 8; ++cb) {
            const float bv = bs[(lane & 15) + (cb << 4)];
            #pragma unroll
            for (int reg = 0; reg < 4; ++reg) acc[tt][cb][reg] += bv;
        }
        #pragma unroll
        for (int reg = 0; reg < 4; ++reg) {
            float s1 = 0.f, s2 = 0.f;
            #pragma unroll
            for (int cb = 0; cb < 8; ++cb) { const float f = acc[tt][cb][reg]; s1 += f; s2 += f * f; }
            #pragma unroll
            for (int m = 1; m < 16; m <<= 1) { s1 += __shfl_xor(s1, m, 64); s2 += __shfl_xor(s2, m, 64); }
            mu[tt][reg] = s1 * (1.f / 128.f);
            inv[tt][reg] = rsqrtf(s2 * (1.f / 128.f) - mu[tt][reg] * mu[tt][reg] + 1e-5f);
        }
    }

    #pragma unroll
    for (int tt = 0; tt < 2; ++tt)
        #pragma unroll
        for (int cb = 0; cb < 8; ++cb) {
            const int c = (lane & 15) + (cb << 4);
            const float gv = gs[c], btv = bt[c];
            #pragma unroll
            for (int reg = 0; reg < 4; ++reg) {
                const int m = ((lane >> 4) << 2) + reg;
                const float v = (acc[tt][cb][reg] - mu[tt][reg]) * inv[tt][reg] * gv + btv;
                ol[(w * 32 + tt * 16 + m) * DF + c] = f2bf(fmaxf(v, 0.f));
            }
        }
    __syncthreads();

    if (COLMAX) {
        const int c = tid & 127;
        const int r0 = (tid >> 7) * 64;
        float m = 0.f;
        #pragma unroll 8
        for (int r = r0; r < r0 + 64; ++r)
            m = fmaxf(m, bf2f(ol[r * DF + c]));
        atomicMax(&cm[c], __float_as_uint(m));
        __syncthreads();
        if (tid < DF) atomicMax(g + tid, cm[tid]);
    } else {
        const int rowbase = blockIdx.x * 128;
        uint4* og = (uint4*)(out + (size_t)rowbase * DF);
        const uint4* olv = (const uint4*)ol;
        #pragma unroll
        for (int i = 0; i < 8; ++i) {
            const int j = tid + 256 * i;
            if (rowbase + (j >> 4) < nrows) og[j] = olv[j];
        }
    }
}

// ---------------- CSR build: bucket sort + single finish kernel ----------------
__global__ __launch_bounds__(256) void bucket_hist(const int* __restrict__ dst,
                                                   int* __restrict__ bhist, int nE)
{
    __shared__ int lh[256];
    lh[threadIdx.x] = 0;
    __syncthreads();
    const int stride = gridDim.x * 256;
    for (int e = blockIdx.x * 256 + threadIdx.x; e < nE; e += stride)
        atomicAdd(&lh[dst[e] >> 8], 1);
    __syncthreads();
    const int v = lh[threadIdx.x];
    if (v) atomicAdd(&bhist[threadIdx.x], v);
}

__global__ __launch_bounds__(256) void bucket_scan(const int* __restrict__ bhist,
                                                   int* __restrict__ bstart,
                                                   int* __restrict__ gcursor, int NB, int nE)
{
    __shared__ int s[256];
    const int t = threadIdx.x;
    const int v = (t < NB) ? bhist[t] : 0;
    s[t] = v;
    __syncthreads();
    for (int off = 1; off < 256; off <<= 1) {
        const int tmp = (t >= off) ? s[t - off] : 0;
        __syncthreads();
        s[t] += tmp;
        __syncthreads();
    }
    const int excl = s[t] - v;
    if (t < NB) { bstart[t] = excl; gcursor[t] = excl; }
    if (t == 0) bstart[NB] = nE;
}

__global__ __launch_bounds__(256) void bucket_scatter(const int* __restrict__ src,
                                                      const int* __restrict__ dst,
                                                      int* __restrict__ gcursor,
                                                      uint2* __restrict__ bbuf, int nE)
{
    __shared__ int lh[256], lsc[256], gb[256];
    __shared__ uint2 lbuf[SCHUNK];
    const int tid = threadIdx.x;
    const int base = blockIdx.x * SCHUNK;
    const int cnt = min(SCHUNK, nE - base);
    lh[tid] = 0;
    __syncthreads();
    int b[8], pos[8]; unsigned sv[8], dv[8];
    #pragma unroll
    for (int i = 0; i < 8; ++i) {
        const int li = i * 256 + tid;
        if (li < cnt) {
            sv[i] = src[base + li]; dv[i] = dst[base + li];
            b[i] = dv[i] >> 8;
            pos[i] = atomicAdd(&lh[b[i]], 1);
        } else b[i] = -1;
    }
    __syncthreads();
    const int v = lh[tid];
    lsc[tid] = v;
    __syncthreads();
    for (int off = 1; off < 256; off <<= 1) {
        const int tmp = (tid >= off) ? lsc[tid - off] : 0;
        __syncthreads();
        lsc[tid] += tmp;
        __syncthreads();
    }
    const int excl = lsc[tid] - v;
    __syncthreads();
    lsc[tid] = excl;
    if (v > 0) gb[tid] = atomicAdd(&gcursor[tid], v);
    __syncthreads();
    #pragma unroll
    for (int i = 0; i < 8; ++i)
        if (b[i] >= 0) lbuf[lsc[b[i]] + pos[i]] = make_uint2(sv[i], dv[i]);
    __syncthreads();
    for (int j = tid; j < cnt; j += 256) {
        const uint2 p = lbuf[j];
        const int bb = p.y >> 8;
        bbuf[gb[bb] + (j - lsc[bb])] = p;
    }
}

__global__ __launch_bounds__(256) void bucket_finish(const uint2* __restrict__ bbuf,
                                                     const int* __restrict__ bstart,
                                                     int* __restrict__ start,
                                                     int* __restrict__ csr_src,
                                                     int n, int nE)
{
    __shared__ int lh[256], ns[256], lc[256];
    const int t = threadIdx.x;
    const int b = blockIdx.x;
    lh[t] = 0; lc[t] = 0;
    __syncthreads();
    const int lo = bstart[b], hi = bstart[b + 1];
    for (int j = lo + t; j < hi; j += 256)
        atomicAdd(&lh[bbuf[j].y & 255], 1);
    __syncthreads();
    const int v = lh[t];
    ns[t] = v;
    __syncthreads();
    for (int off = 1; off < 256; off <<= 1) {
        const int tmp = (t >= off) ? ns[t - off] : 0;
        __syncthreads();
        ns[t] += tmp;
        __syncthreads();
    }
    const int excl = ns[t] - v;
    ns[t] = excl + lo;
    const int node = (b << 8) + t;
    if (node < n) start[node] = ns[t];
    if (b == gridDim.x - 1 && t == 0) start[n] = nE;
    __syncthreads();
    for (int j = lo + t; j < hi; j += 256) {
        const uint2 p = bbuf[j];
        const int loc = p.y & 255;
        const int ofs = atomicAdd(&lc[loc], 1);
        csr_src[ns[loc] + ofs] = p.x;
    }
}

// ---------------- pull max (bf16), 4-way ILP ----------------
__global__ __launch_bounds__(256) void pull_max(const ushort* __restrict__ h,
                                                const int* __restrict__ csr_src,
                                                const int* __restrict__ start,
                                                ushort* __restrict__ neigh, int n)
{
    const int lane = threadIdx.x & 63;
    const int wid = threadIdx.x >> 6;
    const int node = blockIdx.x * 4 + wid;
    if (node >= n) return;
    const int s0 = start[node];
    const int s1 = start[node + 1];
    unsigned mlo = 0, mhi = 0;
    for (int base = s0; base < s1; base += 64) {
        const int cnt = min(64, s1 - base);
        const int myidx = (base + lane < s1) ? csr_src[base + lane] : 0;
        int j = 0;
        for (; j + 4 <= cnt; j += 4) {
            const int sa = __shfl(myidx, j, 64);
            const int sb = __shfl(myidx, j + 1, 64);
            const int sc = __shfl(myidx, j + 2, 64);
            const int sd = __shfl(myidx, j + 3, 64);
            const unsigned va = ((const unsigned*)(h + (size_t)sa * DF))[lane];
            const unsigned vb = ((const unsigned*)(h + (size_t)sb * DF))[lane];
            const unsigned vc = ((const unsigned*)(h + (size_t)sc * DF))[lane];
            const unsigned vd = ((const unsigned*)(h + (size_t)sd * DF))[lane];
            mlo = max(mlo, max(max(va & 0xffffu, vb & 0xffffu), max(vc & 0xffffu, vd & 0xffffu)));
            mhi = max(mhi, max(max(va >> 16, vb >> 16), max(vc >> 16, vd >> 16)));
        }
        for (; j < cnt; ++j) {
            const int sa = __shfl(myidx, j, 64);
            const unsigned va = ((const unsigned*)(h + (size_t)sa * DF))[lane];
            mlo = max(mlo, va & 0xffffu);
            mhi = max(mhi, va >> 16);
        }
    }
    ((unsigned*)(neigh + (size_t)node * DF))[lane] = mlo | (mhi << 16);
}

// ---------------- readout head ----------------
__global__ __launch_bounds__(128) void head(const float* __restrict__ g,
                                            const float* __restrict__ Wfc1,
                                            const float* __restrict__ bfc1,
                                            const float* __restrict__ Wfc,
                                            const float* __restrict__ bfc,
                                            float* __restrict__ out)
{
    __shared__ float gsh[DF];
    __shared__ float tsh[DF];
    const int t = threadIdx.x;
    gsh[t] = g[t];
    __syncthreads();
    float acc = bfc1[t];
    #pragma unroll 8
    for (int k = 0; k < DF; ++k) acc = fmaf(gsh[k], Wfc1[k * DF + t], acc);
    tsh[t] = acc * Wfc[t];
    __syncthreads();
    if (t == 0) {
        float s = 0.f;
        for (int i = 0; i < DF; ++i) s += tsh[i];
        out[0] = s + bfc[0];
    }
}

extern "C" void kernel_launch(void* const* d_in, const int* in_sizes, int n_in,
                              void* d_out, int out_size, void* d_ws, size_t ws_size,
                              hipStream_t stream) {
    const float* x0     = (const float*)d_in[0];
    const int*   src    = (const int*)d_in[1];
    const int*   dst    = (const int*)d_in[2];
    const float* Wpool0 = (const float*)d_in[3];
    const float* bpool0 = (const float*)d_in[4];
    const float* Wself0 = (const float*)d_in[5];
    const float* Wneigh0= (const float*)d_in[6];
    const float* bias0  = (const float*)d_in[7];
    const float* gamma0 = (const float*)d_in[8];
    const float* beta0  = (const float*)d_in[9];
    const float* Wpool1 = (const float*)d_in[10];
    const float* bpool1 = (const float*)d_in[11];
    const float* Wself1 = (const float*)d_in[12];
    const float* Wneigh1= (const float*)d_in[13];
    const float* bias1  = (const float*)d_in[14];
    const float* gamma1 = (const float*)d_in[15];
    const float* beta1  = (const float*)d_in[16];
    const float* Wfc1   = (const float*)d_in[17];
    const float* bfc1   = (const float*)d_in[18];
    const float* Wfc    = (const float*)d_in[19];
    const float* bfc    = (const float*)d_in[20];

    const int N  = in_sizes[0] / DF;   // 50000
    const int nE = in_sizes[1];        // 800000
    const size_t bufElems = (size_t)N * DF;
    const int NB = (N + 255) >> 8;     // 196 buckets

    ushort* x1b  = (ushort*)d_ws;            // 12.8 MB each
    ushort* hb   = x1b + bufElems;
    ushort* nbuf = hb + bufElems;
    uint2* bbuf  = (uint2*)(nbuf + bufElems); // nE pairs = 6.4 MB
    ushort* wfp0 = (ushort*)(bbuf + nE);
    ushort* wfp1 = wfp0 + 16384;
    ushort* wfc0 = wfp1 + 16384;
    ushort* wfc1 = wfc0 + 32768;
    unsigned* g  = (unsigned*)(wfc1 + 32768);
    int* start   = (int*)(g + DF);       // N+1
    int* csr_src = start + N + 1;        // nE
    int* bhist   = csr_src + nE;         // 256
    int* bstart  = bhist + 256;          // 257
    int* gcursor = bstart + 257;         // 256

    const dim3 gP((N + 3) / 4);
    const dim3 gM((N + 127) / 128);      // 391 MFMA-GEMM blocks
    const int nSC = (nE + SCHUNK - 1) / SCHUNK;   // 391

    // ---- prep: all weight fragments + zero bhist/g (1 kernel) ----
    prep_all<<<49, 256, 0, stream>>>(Wpool0, Wpool1, Wself0, Wneigh0, Wself1, Wneigh1,
                                     wfp0, wfp1, wfc0, wfc1, bhist, g);

    // ---- CSR build (bucketed, owner-computes) ----
    bucket_hist<<<256, 256, 0, stream>>>(dst, bhist, nE);
    bucket_scan<<<1, 256, 0, stream>>>(bhist, bstart, gcursor, NB, nE);
    bucket_scatter<<<nSC, 256, 0, stream>>>(src, dst, gcursor, bbuf, nE);
    bucket_finish<<<NB, 256, 0, stream>>>(bbuf, bstart, start, csr_src, N, nE);

    // ---- layer 0 (A-operand direct from fp32 x0) ----
    gemm_pool<1><<<gM, 256, 0, stream>>>(nullptr, x0, wfp0, bpool0, hb, N);
    pull_max<<<gP, 256, 0, stream>>>(hb, csr_src, start, nbuf, N);
    gemm_fused_ln<1, 0><<<gM, 256, 0, stream>>>(nullptr, x0, nbuf, wfc0, bias0, gamma0, beta0, x1b, nullptr, N);

    // ---- layer 1 (colmax fused into the final GEMM epilogue) ----
    gemm_pool<0><<<gM, 256, 0, stream>>>(x1b, nullptr, wfp1, bpool1, hb, N);
    pull_max<<<gP, 256, 0, stream>>>(hb, csr_src, start, nbuf, N);
    gemm_fused_ln<0, 1><<<gM, 256, 0, stream>>>(x1b, nullptr, nbuf, wfc1, bias1, gamma1, beta1, nullptr, g, N);

    // ---- readout ----
    head<<<1, 128, 0, stream>>>((const float*)g, Wfc1, bfc1, Wfc, bfc, (float*)d_out);
}

// Round 20
// 169.788 us; speedup vs baseline: 1.1428x; 1.1428x over previous
//
#include <hip/hip_runtime.h>

#define DF 128
#define SCHUNK 2048

typedef __attribute__((ext_vector_type(8))) short short8;
typedef __attribute__((ext_vector_type(4))) float f32x4;

__device__ __forceinline__ ushort f2bf(float f) {
    unsigned u = __float_as_uint(f);
    return (ushort)((u + 0x7fffu + ((u >> 16) & 1u)) >> 16);   // RNE
}
__device__ __forceinline__ float bf2f(ushort h) {
    return __uint_as_float(((unsigned)h) << 16);
}
// load 8 fp32, convert to 8 bf16 (RNE) in-register -> MFMA A-fragment
__device__ __forceinline__ short8 ld_a_f32(const float* p) {
    const float4 u = ((const float4*)p)[0];
    const float4 v = ((const float4*)p)[1];
    short8 r;
    r[0] = (short)f2bf(u.x); r[1] = (short)f2bf(u.y);
    r[2] = (short)f2bf(u.z); r[3] = (short)f2bf(u.w);
    r[4] = (short)f2bf(v.x); r[5] = (short)f2bf(v.y);
    r[6] = (short)f2bf(v.z); r[7] = (short)f2bf(v.w);
    return r;
}

// ---------------- prep_all: all 4 weight-fragment buffers + zero bhist/g, one kernel ----------------
__global__ __launch_bounds__(256) void prep_all(const float* __restrict__ Wpool0,
                                                const float* __restrict__ Wpool1,
                                                const float* __restrict__ Wself0,
                                                const float* __restrict__ Wneigh0,
                                                const float* __restrict__ Wself1,
                                                const float* __restrict__ Wneigh1,
                                                ushort* __restrict__ wfp0,
                                                ushort* __restrict__ wfp1,
                                                ushort* __restrict__ wfc0,
                                                ushort* __restrict__ wfc1,
                                                int* __restrict__ bhist,
                                                unsigned* __restrict__ g)
{
    const int tid = threadIdx.x;
    if (blockIdx.x == 48) {
        bhist[tid] = 0;
        if (tid < DF) g[tid] = 0;
        return;
    }
    const int e = blockIdx.x * 256 + tid;
    const float *Wa, *Wb; ushort* out; int le;
    if (e < 2048)      { Wa = Wpool0; Wb = Wpool0;  out = wfp0; le = e; }
    else if (e < 4096) { Wa = Wpool1; Wb = Wpool1;  out = wfp1; le = e - 2048; }
    else if (e < 8192) { Wa = Wself0; Wb = Wneigh0; out = wfc0; le = e - 4096; }
    else               { Wa = Wself1; Wb = Wneigh1; out = wfc1; le = e - 8192; }
    const int kstep = le >> 9;
    const int cb = (le >> 6) & 7;
    const int lane = le & 63;
    const int c = cb * 16 + (lane & 15);
    const int k0 = kstep * 32 + ((lane >> 4) << 3);
    ushort r[8];
    #pragma unroll
    for (int i = 0; i < 8; ++i) {
        const int k = k0 + i;
        const float v = (k < DF) ? Wa[k * DF + c] : Wb[(k - DF) * DF + c];
        r[i] = f2bf(v);
    }
    uint4 o;
    o.x = r[0] | ((unsigned)r[1] << 16);
    o.y = r[2] | ((unsigned)r[3] << 16);
    o.z = r[4] | ((unsigned)r[5] << 16);
    o.w = r[6] | ((unsigned)r[7] << 16);
    ((uint4*)out)[le] = o;
}

// ---------------- MFMA pool GEMM: out = relu(x @ Wpool + b), 128 rows/block ----------------
template<int AF32>
__global__ __launch_bounds__(256) void gemm_pool(const ushort* __restrict__ xb,
                                                 const float* __restrict__ xf,
                                                 const ushort* __restrict__ wf,
                                                 const float* __restrict__ bias,
                                                 ushort* __restrict__ out, int nrows)
{
    __shared__ ushort wl[16384];
    __shared__ float bs[DF];
    const int tid = threadIdx.x;
    {
        const uint4* s = (const uint4*)wf;
        uint4* d = (uint4*)wl;
        #pragma unroll
        for (int i = 0; i < 8; ++i) d[tid + 256 * i] = s[tid + 256 * i];
        if (tid < DF) bs[tid] = bias[tid];
    }
    __syncthreads();

    const int lane = tid & 63;
    const int w = tid >> 6;
    const int rb = blockIdx.x * 128 + w * 32;
    const int ar0 = min(rb + (lane & 15), nrows - 1);
    const int ar1 = min(rb + 16 + (lane & 15), nrows - 1);
    const int ko = (lane >> 4) << 3;

    f32x4 acc[2][8];
    #pragma unroll
    for (int tt = 0; tt < 2; ++tt)
        #pragma unroll
        for (int cb = 0; cb < 8; ++cb) acc[tt][cb] = (f32x4){0.f, 0.f, 0.f, 0.f};

    #pragma unroll
    for (int ks = 0; ks < 4; ++ks) {
        short8 a0, a1;
        if (AF32) {
            a0 = ld_a_f32(xf + (size_t)ar0 * DF + ko + ks * 32);
            a1 = ld_a_f32(xf + (size_t)ar1 * DF + ko + ks * 32);
        } else {
            a0 = *(const short8*)(xb + (size_t)ar0 * DF + ko + ks * 32);
            a1 = *(const short8*)(xb + (size_t)ar1 * DF + ko + ks * 32);
        }
        #pragma unroll
        for (int cb = 0; cb < 8; ++cb) {
            const short8 b = ((const short8*)wl)[(ks * 8 + cb) * 64 + lane];
            acc[0][cb] = __builtin_amdgcn_mfma_f32_16x16x32_bf16(a0, b, acc[0][cb], 0, 0, 0);
            acc[1][cb] = __builtin_amdgcn_mfma_f32_16x16x32_bf16(a1, b, acc[1][cb], 0, 0, 0);
        }
    }
    __syncthreads();   // wl dead as weights; reuse as out staging (32KB)

    ushort* ol = wl;
    #pragma unroll
    for (int tt = 0; tt < 2; ++tt)
        #pragma unroll
        for (int cb = 0; cb < 8; ++cb) {
            const int c = (lane & 15) + (cb << 4);
            const float bv = bs[c];
            #pragma unroll
            for (int reg = 0; reg < 4; ++reg) {
                const int m = ((lane >> 4) << 2) + reg;
                ol[(w * 32 + tt * 16 + m) * DF + c] = f2bf(fmaxf(acc[tt][cb][reg] + bv, 0.f));
            }
        }
    __syncthreads();

    const int rowbase = blockIdx.x * 128;
    uint4* og = (uint4*)(out + (size_t)rowbase * DF);
    const uint4* olv = (const uint4*)wl;
    #pragma unroll
    for (int i = 0; i < 8; ++i) {
        const int j = tid + 256 * i;
        if (rowbase + (j >> 4) < nrows) og[j] = olv[j];
    }
}

// ---------------- MFMA fused GEMM+LN ----------------
// COLMAX=0: write out rows. COLMAX=1: skip global write, column-max -> atomicMax(g).
template<int AF32, int COLMAX>
__global__ __launch_bounds__(256) void gemm_fused_ln(const ushort* __restrict__ xb,
                                                     const float* __restrict__ xf,
                                                     const ushort* __restrict__ nbuf,
                                                     const ushort* __restrict__ wf,
                                                     const float* __restrict__ bias,
                                                     const float* __restrict__ gamma,
                                                     const float* __restrict__ beta,
                                                     ushort* __restrict__ out,
                                                     unsigned* __restrict__ g, int nrows)
{
    __shared__ ushort wl[32768];
    __shared__ float bs[DF], gs[DF], bt[DF];
    __shared__ unsigned cm[DF];
    const int tid = threadIdx.x;
    {
        const uint4* s = (const uint4*)wf;
        uint4* d = (uint4*)wl;
        #pragma unroll
        for (int i = 0; i < 16; ++i) d[tid + 256 * i] = s[tid + 256 * i];
        if (tid < DF) { bs[tid] = bias[tid]; gs[tid] = gamma[tid]; bt[tid] = beta[tid]; }
        if (COLMAX && tid < DF) cm[tid] = 0;
    }
    __syncthreads();

    const int lane = tid & 63;
    const int w = tid >> 6;
    const int rb = blockIdx.x * 128 + w * 32;
    const int ar0 = min(rb + (lane & 15), nrows - 1);
    const int ar1 = min(rb + 16 + (lane & 15), nrows - 1);
    const int ko = (lane >> 4) << 3;
    const ushort* apn0 = nbuf + (size_t)ar0 * DF + ko;
    const ushort* apn1 = nbuf + (size_t)ar1 * DF + ko;

    f32x4 acc[2][8];
    #pragma unroll
    for (int tt = 0; tt < 2; ++tt)
        #pragma unroll
        for (int cb = 0; cb < 8; ++cb) acc[tt][cb] = (f32x4){0.f, 0.f, 0.f, 0.f};

    #pragma unroll
    for (int ks = 0; ks < 8; ++ks) {
        short8 a0, a1;
        if (ks < 4) {
            if (AF32) {
                a0 = ld_a_f32(xf + (size_t)ar0 * DF + ko + ks * 32);
                a1 = ld_a_f32(xf + (size_t)ar1 * DF + ko + ks * 32);
            } else {
                a0 = *(const short8*)(xb + (size_t)ar0 * DF + ko + ks * 32);
                a1 = *(const short8*)(xb + (size_t)ar1 * DF + ko + ks * 32);
            }
        } else {
            a0 = *(const short8*)(apn0 + (ks - 4) * 32);
            a1 = *(const short8*)(apn1 + (ks - 4) * 32);
        }
        #pragma unroll
        for (int cb = 0; cb < 8; ++cb) {
            const short8 b = ((const short8*)wl)[(ks * 8 + cb) * 64 + lane];
            acc[0][cb] = __builtin_amdgcn_mfma_f32_16x16x32_bf16(a0, b, acc[0][cb], 0, 0, 0);
            acc[1][cb] = __builtin_amdgcn_mfma_f32_16x16x32_bf16(a1, b, acc[1][cb], 0, 0, 0);
        }
    }

    float mu[2][4], inv[2][4];
    #pragma unroll
    for (int tt = 0; tt < 2; ++tt) {
        #pragma unroll
        for (int cb = 0; cb < 8; ++cb) {
            const float bv = bs[(lane & 15) + (cb << 4)];
            #pragma unroll
            for (int reg = 0; reg < 4; ++reg) acc[tt][cb][reg] += bv;
        }
        #pragma unroll
        for (int reg = 0; reg < 4; ++reg) {
            float s1 = 0.f, s2 = 0.f;
            #pragma unroll
            for (int cb = 0; cb < 8; ++cb) { const float f = acc[tt][cb][reg]; s1 += f; s2 += f * f; }
            #pragma unroll
            for (int m = 1; m < 16; m <<= 1) { s1 += __shfl_xor(s1, m, 64); s2 += __shfl_xor(s2, m, 64); }
            mu[tt][reg] = s1 * (1.f / 128.f);
            inv[tt][reg] = rsqrtf(s2 * (1.f / 128.f) - mu[tt][reg] * mu[tt][reg] + 1e-5f);
        }
    }
    __syncthreads();   // wl weights dead; reuse as out staging

    ushort* ol = wl;
    #pragma unroll
    for (int tt = 0; tt < 2; ++tt)
        #pragma unroll
        for (int cb = 0; cb < 8; ++cb) {
            const int c = (lane & 15) + (cb << 4);
            const float gv = gs[c], btv = bt[c];
            #pragma unroll
            for (int reg = 0; reg < 4; ++reg) {
                const int m = ((lane >> 4) << 2) + reg;
                const float v = (acc[tt][cb][reg] - mu[tt][reg]) * inv[tt][reg] * gv + btv;
                ol[(w * 32 + tt * 16 + m) * DF + c] = f2bf(fmaxf(v, 0.f));
            }
        }
    __syncthreads();

    if (COLMAX) {
        // per-column max of the 128x128 tile (clamped duplicate rows are harmless for max)
        const int c = tid & 127;
        const int r0 = (tid >> 7) * 64;
        float m = 0.f;
        #pragma unroll 8
        for (int r = r0; r < r0 + 64; ++r)
            m = fmaxf(m, bf2f(ol[r * DF + c]));
        atomicMax(&cm[c], __float_as_uint(m));
        __syncthreads();
        if (tid < DF) atomicMax(g + tid, cm[tid]);
    } else {
        const int rowbase = blockIdx.x * 128;
        uint4* og = (uint4*)(out + (size_t)rowbase * DF);
        const uint4* olv = (const uint4*)wl;
        #pragma unroll
        for (int i = 0; i < 8; ++i) {
            const int j = tid + 256 * i;
            if (rowbase + (j >> 4) < nrows) og[j] = olv[j];
        }
    }
}

// ---------------- CSR build: bucket sort + single finish kernel ----------------
__global__ __launch_bounds__(256) void bucket_hist(const int* __restrict__ dst,
                                                   int* __restrict__ bhist, int nE)
{
    __shared__ int lh[256];
    lh[threadIdx.x] = 0;
    __syncthreads();
    const int stride = gridDim.x * 256;
    for (int e = blockIdx.x * 256 + threadIdx.x; e < nE; e += stride)
        atomicAdd(&lh[dst[e] >> 8], 1);
    __syncthreads();
    const int v = lh[threadIdx.x];
    if (v) atomicAdd(&bhist[threadIdx.x], v);
}

__global__ __launch_bounds__(256) void bucket_scan(const int* __restrict__ bhist,
                                                   int* __restrict__ bstart,
                                                   int* __restrict__ gcursor, int NB, int nE)
{
    __shared__ int s[256];
    const int t = threadIdx.x;
    const int v = (t < NB) ? bhist[t] : 0;
    s[t] = v;
    __syncthreads();
    for (int off = 1; off < 256; off <<= 1) {
        const int tmp = (t >= off) ? s[t - off] : 0;
        __syncthreads();
        s[t] += tmp;
        __syncthreads();
    }
    const int excl = s[t] - v;
    if (t < NB) { bstart[t] = excl; gcursor[t] = excl; }
    if (t == 0) bstart[NB] = nE;
}

__global__ __launch_bounds__(256) void bucket_scatter(const int* __restrict__ src,
                                                      const int* __restrict__ dst,
                                                      int* __restrict__ gcursor,
                                                      uint2* __restrict__ bbuf, int nE)
{
    __shared__ int lh[256], lsc[256], gb[256];
    __shared__ uint2 lbuf[SCHUNK];
    const int tid = threadIdx.x;
    const int base = blockIdx.x * SCHUNK;
    const int cnt = min(SCHUNK, nE - base);
    lh[tid] = 0;
    __syncthreads();
    int b[8], pos[8]; unsigned sv[8], dv[8];
    #pragma unroll
    for (int i = 0; i < 8; ++i) {
        const int li = i * 256 + tid;
        if (li < cnt) {
            sv[i] = src[base + li]; dv[i] = dst[base + li];
            b[i] = dv[i] >> 8;
            pos[i] = atomicAdd(&lh[b[i]], 1);
        } else b[i] = -1;
    }
    __syncthreads();
    const int v = lh[tid];
    lsc[tid] = v;
    __syncthreads();
    for (int off = 1; off < 256; off <<= 1) {
        const int tmp = (tid >= off) ? lsc[tid - off] : 0;
        __syncthreads();
        lsc[tid] += tmp;
        __syncthreads();
    }
    const int excl = lsc[tid] - v;
    __syncthreads();
    lsc[tid] = excl;
    if (v > 0) gb[tid] = atomicAdd(&gcursor[tid], v);
    __syncthreads();
    #pragma unroll
    for (int i = 0; i < 8; ++i)
        if (b[i] >= 0) lbuf[lsc[b[i]] + pos[i]] = make_uint2(sv[i], dv[i]);
    __syncthreads();
    for (int j = tid; j < cnt; j += 256) {
        const uint2 p = lbuf[j];
        const int bb = p.y >> 8;
        bbuf[gb[bb] + (j - lsc[bb])] = p;
    }
}

__global__ __launch_bounds__(256) void bucket_finish(const uint2* __restrict__ bbuf,
                                                     const int* __restrict__ bstart,
                                                     int* __restrict__ start,
                                                     int* __restrict__ csr_src,
                                                     int n, int nE)
{
    __shared__ int lh[256], ns[256], lc[256];
    const int t = threadIdx.x;
    const int b = blockIdx.x;
    lh[t] = 0; lc[t] = 0;
    __syncthreads();
    const int lo = bstart[b], hi = bstart[b + 1];
    for (int j = lo + t; j < hi; j += 256)
        atomicAdd(&lh[bbuf[j].y & 255], 1);
    __syncthreads();
    const int v = lh[t];
    ns[t] = v;
    __syncthreads();
    for (int off = 1; off < 256; off <<= 1) {
        const int tmp = (t >= off) ? ns[t - off] : 0;
        __syncthreads();
        ns[t] += tmp;
        __syncthreads();
    }
    const int excl = ns[t] - v;
    ns[t] = excl + lo;
    const int node = (b << 8) + t;
    if (node < n) start[node] = ns[t];
    if (b == gridDim.x - 1 && t == 0) start[n] = nE;
    __syncthreads();
    for (int j = lo + t; j < hi; j += 256) {
        const uint2 p = bbuf[j];
        const int loc = p.y & 255;
        const int ofs = atomicAdd(&lc[loc], 1);
        csr_src[ns[loc] + ofs] = p.x;
    }
}

// ---------------- pull max (bf16), 4-way ILP ----------------
__global__ __launch_bounds__(256) void pull_max(const ushort* __restrict__ h,
                                                const int* __restrict__ csr_src,
                                                const int* __restrict__ start,
                                                ushort* __restrict__ neigh, int n)
{
    const int lane = threadIdx.x & 63;
    const int wid = threadIdx.x >> 6;
    const int node = blockIdx.x * 4 + wid;
    if (node >= n) return;
    const int s0 = start[node];
    const int s1 = start[node + 1];
    unsigned mlo = 0, mhi = 0;
    for (int base = s0; base < s1; base += 64) {
        const int cnt = min(64, s1 - base);
        const int myidx = (base + lane < s1) ? csr_src[base + lane] : 0;
        int j = 0;
        for (; j + 4 <= cnt; j += 4) {
            const int sa = __shfl(myidx, j, 64);
            const int sb = __shfl(myidx, j + 1, 64);
            const int sc = __shfl(myidx, j + 2, 64);
            const int sd = __shfl(myidx, j + 3, 64);
            const unsigned va = ((const unsigned*)(h + (size_t)sa * DF))[lane];
            const unsigned vb = ((const unsigned*)(h + (size_t)sb * DF))[lane];
            const unsigned vc = ((const unsigned*)(h + (size_t)sc * DF))[lane];
            const unsigned vd = ((const unsigned*)(h + (size_t)sd * DF))[lane];
            mlo = max(mlo, max(max(va & 0xffffu, vb & 0xffffu), max(vc & 0xffffu, vd & 0xffffu)));
            mhi = max(mhi, max(max(va >> 16, vb >> 16), max(vc >> 16, vd >> 16)));
        }
        for (; j < cnt; ++j) {
            const int sa = __shfl(myidx, j, 64);
            const unsigned va = ((const unsigned*)(h + (size_t)sa * DF))[lane];
            mlo = max(mlo, va & 0xffffu);
            mhi = max(mhi, va >> 16);
        }
    }
    ((unsigned*)(neigh + (size_t)node * DF))[lane] = mlo | (mhi << 16);
}

// ---------------- readout head ----------------
__global__ __launch_bounds__(128) void head(const float* __restrict__ g,
                                            const float* __restrict__ Wfc1,
                                            const float* __restrict__ bfc1,
                                            const float* __restrict__ Wfc,
                                            const float* __restrict__ bfc,
                                            float* __restrict__ out)
{
    __shared__ float gsh[DF];
    __shared__ float tsh[DF];
    const int t = threadIdx.x;
    gsh[t] = g[t];
    __syncthreads();
    float acc = bfc1[t];
    #pragma unroll 8
    for (int k = 0; k < DF; ++k) acc = fmaf(gsh[k], Wfc1[k * DF + t], acc);
    tsh[t] = acc * Wfc[t];
    __syncthreads();
    if (t == 0) {
        float s = 0.f;
        for (int i = 0; i < DF; ++i) s += tsh[i];
        out[0] = s + bfc[0];
    }
}

extern "C" void kernel_launch(void* const* d_in, const int* in_sizes, int n_in,
                              void* d_out, int out_size, void* d_ws, size_t ws_size,
                              hipStream_t stream) {
    const float* x0     = (const float*)d_in[0];
    const int*   src    = (const int*)d_in[1];
    const int*   dst    = (const int*)d_in[2];
    const float* Wpool0 = (const float*)d_in[3];
    const float* bpool0 = (const float*)d_in[4];
    const float* Wself0 = (const float*)d_in[5];
    const float* Wneigh0= (const float*)d_in[6];
    const float* bias0  = (const float*)d_in[7];
    const float* gamma0 = (const float*)d_in[8];
    const float* beta0  = (const float*)d_in[9];
    const float* Wpool1 = (const float*)d_in[10];
    const float* bpool1 = (const float*)d_in[11];
    const float* Wself1 = (const float*)d_in[12];
    const float* Wneigh1= (const float*)d_in[13];
    const float* bias1  = (const float*)d_in[14];
    const float* gamma1 = (const float*)d_in[15];
    const float* beta1  = (const float*)d_in[16];
    const float* Wfc1   = (const float*)d_in[17];
    const float* bfc1   = (const float*)d_in[18];
    const float* Wfc    = (const float*)d_in[19];
    const float* bfc    = (const float*)d_in[20];

    const int N  = in_sizes[0] / DF;   // 50000
    const int nE = in_sizes[1];        // 800000
    const size_t bufElems = (size_t)N * DF;
    const int NB = (N + 255) >> 8;     // 196 buckets

    ushort* x1b  = (ushort*)d_ws;            // 12.8 MB each
    ushort* hb   = x1b + bufElems;
    ushort* nbuf = hb + bufElems;
    uint2* bbuf  = (uint2*)(nbuf + bufElems); // nE pairs = 6.4 MB
    ushort* wfp0 = (ushort*)(bbuf + nE);
    ushort* wfp1 = wfp0 + 16384;
    ushort* wfc0 = wfp1 + 16384;
    ushort* wfc1 = wfc0 + 32768;
    unsigned* g  = (unsigned*)(wfc1 + 32768);
    int* start   = (int*)(g + DF);       // N+1
    int* csr_src = start + N + 1;        // nE
    int* bhist   = csr_src + nE;         // 256
    int* bstart  = bhist + 256;          // 257
    int* gcursor = bstart + 257;         // 256

    const dim3 gP((N + 3) / 4);
    const dim3 gM((N + 127) / 128);      // 391 MFMA-GEMM blocks
    const int nSC = (nE + SCHUNK - 1) / SCHUNK;   // 391

    // ---- prep: all weight fragments + zero bhist/g (1 kernel) ----
    prep_all<<<49, 256, 0, stream>>>(Wpool0, Wpool1, Wself0, Wneigh0, Wself1, Wneigh1,
                                     wfp0, wfp1, wfc0, wfc1, bhist, g);

    // ---- CSR build (bucketed, owner-computes) ----
    bucket_hist<<<256, 256, 0, stream>>>(dst, bhist, nE);
    bucket_scan<<<1, 256, 0, stream>>>(bhist, bstart, gcursor, NB, nE);
    bucket_scatter<<<nSC, 256, 0, stream>>>(src, dst, gcursor, bbuf, nE);
    bucket_finish<<<NB, 256, 0, stream>>>(bbuf, bstart, start, csr_src, N, nE);

    // ---- layer 0 (A-operand direct from fp32 x0) ----
    gemm_pool<1><<<gM, 256, 0, stream>>>(nullptr, x0, wfp0, bpool0, hb, N);
    pull_max<<<gP, 256, 0, stream>>>(hb, csr_src, start, nbuf, N);
    gemm_fused_ln<1, 0><<<gM, 256, 0, stream>>>(nullptr, x0, nbuf, wfc0, bias0, gamma0, beta0, x1b, nullptr, N);

    // ---- layer 1 (colmax fused into the final GEMM epilogue) ----
    gemm_pool<0><<<gM, 256, 0, stream>>>(x1b, nullptr, wfp1, bpool1, hb, N);
    pull_max<<<gP, 256, 0, stream>>>(hb, csr_src, start, nbuf, N);
    gemm_fused_ln<0, 1><<<gM, 256, 0, stream>>>(x1b, nullptr, nbuf, wfc1, bias1, gamma1, beta1, nullptr, g, N);

    // ---- readout ----
    head<<<1, 128, 0, stream>>>((const float*)g, Wfc1, bfc1, Wfc, bfc, (float*)d_out);
}